// Round 3
// baseline (71.817 us; speedup 1.0000x reference)
//
#include <hip/hip_runtime.h>

// SU2 attention, MI355X — round 7: hide the stage barrier.
// Math: logits.real = dot4(q_hat, k_hat); |x*SCALE| <= 0.7071 so softmax
// needs NO max-subtraction -> partials combine by plain sum.
//
// Geometry = round-5 (best measured): 512-thread blocks, 8 waves, QR=4,
// grid (64, 8), LDS 40 KB, 2 blocks/CU -> 4 waves/SIMD.
// Round-7 changes:
//  * Wave-local staging: wave w stages j-slice [w*256, w*256+256) and
//    computes that slice BEFORE __syncthreads (same-wave LDS dep is just
//    lgkmcnt) -> first-slice compute hides the other waves' L2 loads.
//  * Query fragments load directly from GLOBAL (4 broadcast 8-B loads,
//    L2-hit) during staging, not from LDS after the barrier.
//  * Post-barrier j-walk starts at each wave's own slice (wrap mod 32)
//    to decorrelate LDS access across waves.
//  * Butterfly reduction uses packed float2 adds (2 shfl + 1 v_pk_add).
// Output PLANAR: d_out = [32768 reals (i,h,d)], then [32768 imags].

#define S 2048
#define H 8
#define QR 4          // queries per wave (register-tiled)
#define NW 8          // waves per block
#define TPB (NW * 64) // 512 threads

typedef float vf2 __attribute__((ext_vector_type(2)));

__device__ inline float fast_exp2(float x) {
#if __has_builtin(__builtin_amdgcn_exp2f)
    return __builtin_amdgcn_exp2f(x);
#else
    return exp2f(x);
#endif
}

// grid = (64, 8): x = query group (8 waves x 4 q = 32 q/block), y = head.
__global__ __launch_bounds__(TPB, 4) void su2_attn_fused(
        const float* __restrict__ re, const float* __restrict__ im,
        float2* __restrict__ outr, float2* __restrict__ outi) {
    __shared__ float4 vt[S];   // raw spinor (re0, im0, re1, im1), 32 KB
    __shared__ float  nt[S];   // 1/||spinor||, 8 KB

    const int h    = blockIdx.y;
    const int lane = threadIdx.x & 63;
    const int wave = threadIdx.x >> 6;
    const int i_base = (blockIdx.x * NW + wave) * QR;

    const float2* __restrict__ re2 = (const float2*)re;  // input (j, h, d)
    const float2* __restrict__ im2 = (const float2*)im;

    // ---- query fragments straight from global (broadcast loads, L2-hit);
    // issued first so they overlap the staging stores below.
    const float c = 0.70710678118654752440f * 1.44269504088896340736f;
    vf2 qc0[QR], qc1[QR];
#pragma unroll
    for (int r = 0; r < QR; ++r) {
        int i = i_base + r;
        float2 qr = re2[i * H + h];
        float2 qi = im2[i * H + h];
        float ss = qr.x * qr.x + qi.x * qi.x + qr.y * qr.y + qi.y * qi.y;
        float s  = rsqrtf(ss) * c;
        vf2 q0 = {qr.x * s, qi.x * s};
        vf2 q1 = {qr.y * s, qi.y * s};
        qc0[r] = q0;
        qc1[r] = q1;
    }

    // ---- wave-local staging: wave w owns jj-units [4w, 4w+4) (256 j)
#pragma unroll
    for (int it = 0; it < 4; ++it) {
        int j = (wave * 4 + it) * 64 + lane;
        float2 r = re2[j * H + h];
        float2 m = im2[j * H + h];
        float ss = r.x * r.x + m.x * m.x + r.y * r.y + m.y * m.y;
        vt[j] = make_float4(r.x, m.x, r.y, m.y);
        nt[j] = rsqrtf(ss);
    }

    float l[QR];
    vf2 a0[QR], a1[QR];
#pragma unroll
    for (int r = 0; r < QR; ++r) {
        l[r]  = 0.f;
        a0[r] = (vf2){0.f, 0.f};
        a1[r] = (vf2){0.f, 0.f};
    }

    // ---- pre-barrier: compute own slice (only our wave's LDS writes read)
#pragma unroll
    for (int t = 0; t < 4; ++t) {
        int j = (wave * 4 + t) * 64 + lane;
        float4 v   = vt[j];
        float  inv = nt[j];
        vf2 v0 = {v.x, v.y};
        vf2 v1 = {v.z, v.w};
#pragma unroll
        for (int r = 0; r < QR; ++r) {
            vf2 d2 = __builtin_elementwise_fma(qc1[r], v1, qc0[r] * v0);
            float p = fast_exp2((d2.x + d2.y) * inv);
            l[r] += p;
            vf2 pp = {p, p};
            a0[r] = __builtin_elementwise_fma(pp, v0, a0[r]);
            a1[r] = __builtin_elementwise_fma(pp, v1, a1[r]);
        }
    }
    __syncthreads();

    // ---- post-barrier: remaining 28 slices, starting past our own (wrap)
#pragma unroll 4
    for (int t = 4; t < 32; ++t) {
        int jju = (wave * 4 + t) & 31;
        int j = jju * 64 + lane;
        float4 v   = vt[j];                     // ds_read_b128, conflict-free
        float  inv = nt[j];
        vf2 v0 = {v.x, v.y};
        vf2 v1 = {v.z, v.w};
#pragma unroll
        for (int r = 0; r < QR; ++r) {
            vf2 d2 = __builtin_elementwise_fma(qc1[r], v1, qc0[r] * v0);
            float p = fast_exp2((d2.x + d2.y) * inv);
            l[r] += p;
            vf2 pp = {p, p};
            a0[r] = __builtin_elementwise_fma(pp, v0, a0[r]);
            a1[r] = __builtin_elementwise_fma(pp, v1, a1[r]);
        }
    }

    // ---- butterfly sum all-reduce across 64 lanes (plain sums, pk adds)
#pragma unroll
    for (int r = 0; r < QR; ++r) {
#pragma unroll
        for (int m = 32; m >= 1; m >>= 1) {
            l[r] += __shfl_xor(l[r], m, 64);
            vf2 t0, t1;
            t0.x = __shfl_xor(a0[r].x, m, 64);
            t0.y = __shfl_xor(a0[r].y, m, 64);
            t1.x = __shfl_xor(a1[r].x, m, 64);
            t1.y = __shfl_xor(a1[r].y, m, 64);
            a0[r] += t0;                        // v_pk_add_f32
            a1[r] += t1;
        }
    }

    if (lane == 0) {
#pragma unroll
        for (int r = 0; r < QR; ++r) {
            float invl = 1.0f / l[r];
            int i = i_base + r;
            // planar: real plane then imag plane, each (i, h, d) as float2
            outr[i * H + h] = make_float2(a0[r].x * invl, a1[r].x * invl);
            outi[i * H + h] = make_float2(a0[r].y * invl, a1[r].y * invl);
        }
    }
}

extern "C" void kernel_launch(void* const* d_in, const int* in_sizes, int n_in,
                              void* d_out, int out_size, void* d_ws, size_t ws_size,
                              hipStream_t stream) {
    const float* re = (const float*)d_in[0];
    const float* im = (const float*)d_in[1];
    float2* outr = (float2*)d_out;    // reals: 16384 float2
    float2* outi = outr + S * H;      // imags
    (void)d_ws; (void)ws_size;

    su2_attn_fused<<<dim3(S / (NW * QR), H), dim3(TPB), 0, stream>>>(re, im, outr, outi);
}

// Round 4
// 68.599 us; speedup vs baseline: 1.0469x; 1.0469x over previous
//
#include <hip/hip_runtime.h>

// SU2 attention, MI355X — round 8: r5 revert + query-pair-packed dots.
// Math: logits.real = dot4(q_hat, k_hat); |x*SCALE| <= 0.7071 so softmax
// needs NO max-subtraction -> partials combine by plain sum.
//
// Geometry = round-5 (measured best, 68.9): 512-thread blocks, 8 waves,
// QR=4, grid (64, 8), LDS 40 KB, 2 blocks/CU -> 4 waves/SIMD.
// Single change vs r5: the logit dot-products are packed over QUERY PAIRS
// (v_pk_fma_f32 lanes hold r and r+1), with per-j spinor components
// broadcast to both halves (op_sel splat):
//   per 4 queries: 8 pk_fma/mul + 2 pk_mul(inv) = 10 slots
//   vs r5's 16 (pk_mul + pk_fma + v_add + v_mul per query).
// Accumulation (a0/a1 per query, packed over complex dim) unchanged.
// Output PLANAR: d_out = [32768 reals (i,h,d)], then [32768 imags].

#define S 2048
#define H 8
#define QR 4          // queries per wave (register-tiled)
#define NW 8          // waves per block
#define TPB (NW * 64) // 512 threads

typedef float vf2 __attribute__((ext_vector_type(2)));

__device__ inline float fast_exp2(float x) {
#if __has_builtin(__builtin_amdgcn_exp2f)
    return __builtin_amdgcn_exp2f(x);
#else
    return exp2f(x);
#endif
}

// grid = (64, 8): x = query group (8 waves x 4 q = 32 q/block), y = head.
__global__ __launch_bounds__(TPB, 4) void su2_attn_fused(
        const float* __restrict__ re, const float* __restrict__ im,
        float2* __restrict__ outr, float2* __restrict__ outi) {
    __shared__ float4 vt[S];   // raw spinor (re0, im0, re1, im1), 32 KB
    __shared__ float  nt[S];   // 1/||spinor||, 8 KB

    const int h    = blockIdx.y;
    const int lane = threadIdx.x & 63;
    const int wave = threadIdx.x >> 6;
    const int i_base = (blockIdx.x * NW + wave) * QR;

    // ---- stage this head's table into LDS (strided 8B loads, L2-resident)
    const float2* __restrict__ re2 = (const float2*)re;  // input (j, h, d)
    const float2* __restrict__ im2 = (const float2*)im;
#pragma unroll
    for (int k = 0; k < S / TPB; ++k) {
        int j = k * TPB + threadIdx.x;
        float2 r = re2[j * H + h];
        float2 m = im2[j * H + h];
        float ss = r.x * r.x + m.x * m.x + r.y * r.y + m.y * m.y;
        vt[j] = make_float4(r.x, m.x, r.y, m.y);
        nt[j] = rsqrtf(ss);
    }
    __syncthreads();

    // ---- query fragments, transposed into r-pair packing.
    // Qx01 = {q0.re0*s0, q1.re0*s1}, etc.; s = c / ||q||.
    const float c = 0.70710678118654752440f * 1.44269504088896340736f;
    float4 qv[QR]; float qs[QR];
#pragma unroll
    for (int r = 0; r < QR; ++r) {
        qv[r] = vt[i_base + r];               // LDS broadcast
        qs[r] = nt[i_base + r] * c;
    }
    vf2 Qx01 = {qv[0].x * qs[0], qv[1].x * qs[1]};
    vf2 Qy01 = {qv[0].y * qs[0], qv[1].y * qs[1]};
    vf2 Qz01 = {qv[0].z * qs[0], qv[1].z * qs[1]};
    vf2 Qw01 = {qv[0].w * qs[0], qv[1].w * qs[1]};
    vf2 Qx23 = {qv[2].x * qs[2], qv[3].x * qs[3]};
    vf2 Qy23 = {qv[2].y * qs[2], qv[3].y * qs[3]};
    vf2 Qz23 = {qv[2].z * qs[2], qv[3].z * qs[3]};
    vf2 Qw23 = {qv[2].w * qs[2], qv[3].w * qs[3]};

    float l[QR];
    vf2 a0[QR], a1[QR];
#pragma unroll
    for (int r = 0; r < QR; ++r) {
        l[r]  = 0.f;
        a0[r] = (vf2){0.f, 0.f};
        a1[r] = (vf2){0.f, 0.f};
    }

    // ---- main loop: j split over 64 lanes, 32 iters
#pragma unroll 4
    for (int jj = 0; jj < S / 64; ++jj) {
        int j = jj * 64 + lane;
        float4 v   = vt[j];                     // ds_read_b128, conflict-free
        float  inv = nt[j];
        // broadcast splats (op_sel lo,lo on the pk ops)
        vf2 vx = {v.x, v.x};
        vf2 vy = {v.y, v.y};
        vf2 vz = {v.z, v.z};
        vf2 vw = {v.w, v.w};
        vf2 ii = {inv, inv};
        // two logits per pk chain
        vf2 s01 = Qx01 * vx;
        s01 = __builtin_elementwise_fma(Qy01, vy, s01);
        s01 = __builtin_elementwise_fma(Qz01, vz, s01);
        s01 = __builtin_elementwise_fma(Qw01, vw, s01);
        vf2 s23 = Qx23 * vx;
        s23 = __builtin_elementwise_fma(Qy23, vy, s23);
        s23 = __builtin_elementwise_fma(Qz23, vz, s23);
        s23 = __builtin_elementwise_fma(Qw23, vw, s23);
        s01 *= ii;
        s23 *= ii;
        float p[QR] = { fast_exp2(s01.x), fast_exp2(s01.y),
                        fast_exp2(s23.x), fast_exp2(s23.y) };
        vf2 v0 = {v.x, v.y};
        vf2 v1 = {v.z, v.w};
#pragma unroll
        for (int r = 0; r < QR; ++r) {
            l[r] += p[r];
            vf2 pp = {p[r], p[r]};
            a0[r] = __builtin_elementwise_fma(pp, v0, a0[r]);
            a1[r] = __builtin_elementwise_fma(pp, v1, a1[r]);
        }
    }

    // ---- butterfly sum all-reduce across 64 lanes (plain sums)
#pragma unroll
    for (int r = 0; r < QR; ++r) {
#pragma unroll
        for (int m = 32; m >= 1; m >>= 1) {
            l[r]    += __shfl_xor(l[r], m, 64);
            a0[r].x += __shfl_xor(a0[r].x, m, 64);
            a0[r].y += __shfl_xor(a0[r].y, m, 64);
            a1[r].x += __shfl_xor(a1[r].x, m, 64);
            a1[r].y += __shfl_xor(a1[r].y, m, 64);
        }
    }

    if (lane == 0) {
#pragma unroll
        for (int r = 0; r < QR; ++r) {
            float invl = 1.0f / l[r];
            int i = i_base + r;
            // planar: real plane then imag plane, each (i, h, d) as float2
            outr[i * H + h] = make_float2(a0[r].x * invl, a1[r].x * invl);
            outi[i * H + h] = make_float2(a0[r].y * invl, a1[r].y * invl);
        }
    }
}

extern "C" void kernel_launch(void* const* d_in, const int* in_sizes, int n_in,
                              void* d_out, int out_size, void* d_ws, size_t ws_size,
                              hipStream_t stream) {
    const float* re = (const float*)d_in[0];
    const float* im = (const float*)d_in[1];
    float2* outr = (float2*)d_out;    // reals: 16384 float2
    float2* outi = outr + S * H;      // imags
    (void)d_ws; (void)ws_size;

    su2_attn_fused<<<dim3(S / (NW * QR), H), dim3(TPB), 0, stream>>>(re, im, outr, outi);
}